// Round 5
// baseline (1793.223 us; speedup 1.0000x reference)
//
#include <hip/hip_runtime.h>
#include <math.h>

#define NPTS 4096
#define KNN 16
#define TBINS 352

// ---------------------------------------------------------------------------
// Kernel A: brute-force 16-NN (exact f64 d2 of f32 diffs), weighted covariance,
// f64 Jacobi eigensolver -> normal (sign-disambiguated), per-cloud max radius.
// ---------------------------------------------------------------------------

// Jacobi rotation on symmetric 3x3 stored as 6 scalars; V columns = eigenvectors.
#define JROT(App, Aqq, Apq, Arp, Arq, V0p, V0q, V1p, V1q, V2p, V2q)            \
  do {                                                                         \
    double apq_ = Apq;                                                         \
    if (fabs(apq_) > 1e-300) {                                                 \
      double tau_ = (Aqq - App) / (2.0 * apq_);                                \
      double t_ = (tau_ >= 0.0) ? 1.0 / (tau_ + sqrt(1.0 + tau_ * tau_))       \
                                : 1.0 / (tau_ - sqrt(1.0 + tau_ * tau_));      \
      double c_ = 1.0 / sqrt(1.0 + t_ * t_);                                   \
      double s_ = t_ * c_;                                                     \
      App = App - t_ * apq_;                                                   \
      Aqq = Aqq + t_ * apq_;                                                   \
      Apq = 0.0;                                                               \
      double u_, w_;                                                           \
      u_ = Arp; w_ = Arq; Arp = c_ * u_ - s_ * w_; Arq = s_ * u_ + c_ * w_;    \
      u_ = V0p; w_ = V0q; V0p = c_ * u_ - s_ * w_; V0q = s_ * u_ + c_ * w_;    \
      u_ = V1p; w_ = V1q; V1p = c_ * u_ - s_ * w_; V1q = s_ * u_ + c_ * w_;    \
      u_ = V2p; w_ = V2q; V2p = c_ * u_ - s_ * w_; V2q = s_ * u_ + c_ * w_;    \
    }                                                                          \
  } while (0)

__global__ __launch_bounds__(256) void knn_normal_kernel(
    const float* __restrict__ verts,        // (8,4096,3)
    float* __restrict__ normals,            // (8*4096,3)
    int* __restrict__ nbr_idx,              // (8*4096,16)
    unsigned int* __restrict__ radius_bits) // (8), f32 bits, init 0
{
  __shared__ float lx[NPTS], ly[NPTS], lz[NPTS];
  const int cloud = blockIdx.x >> 4; // 16 blocks per cloud
  const float* __restrict__ vb = verts + (size_t)cloud * NPTS * 3;
  for (int t = threadIdx.x; t < NPTS; t += 256) {
    float a = vb[3 * t + 0], b = vb[3 * t + 1], c = vb[3 * t + 2];
    lx[t] = a; ly[t] = b; lz[t] = c;
  }
  __syncthreads();

  const int i = ((blockIdx.x & 15) << 8) + (int)threadIdx.x;
  const float xi = lx[i], yi = ly[i], zi = lz[i];

  // top-16 smallest d2, sorted ascending; ties keep lower index (matches top_k)
  double d2l[KNN];
  int il[KNN];
#pragma unroll
  for (int k = 0; k < KNN; ++k) { d2l[k] = 1e300; il[k] = 0; }

  for (int j = 0; j < NPTS; ++j) {
    float dx = __fsub_rn(lx[j], xi);
    float dy = __fsub_rn(ly[j], yi);
    float dz = __fsub_rn(lz[j], zi);
    // exact: products of f32 fit f64; defines the canonical ordering
    double d2 = fma((double)dx, (double)dx,
                    fma((double)dy, (double)dy, (double)dz * (double)dz));
    if (d2 < d2l[KNN - 1]) { // strict: equal-to-worst keeps lower index
      d2l[KNN - 1] = d2;
      il[KNN - 1] = j;
#pragma unroll
      for (int k = KNN - 1; k > 0; --k) {
        if (d2l[k] < d2l[k - 1]) { // strict: stable for ties (index order)
          double td = d2l[k]; d2l[k] = d2l[k - 1]; d2l[k - 1] = td;
          int ti = il[k]; il[k] = il[k - 1]; il[k - 1] = ti;
        }
      }
    }
  }

  // distances, weights, covariance (f64)
  double dist[KNN];
#pragma unroll
  for (int k = 0; k < KNN; ++k) dist[k] = sqrt(d2l[k]);
  const double radius_i = dist[KNN - 1];

  float ddx[KNN], ddy[KNN], ddz[KNN];
  double c00 = 0, c01 = 0, c02 = 0, c11 = 0, c12 = 0, c22 = 0, sw = 0;
#pragma unroll
  for (int k = 0; k < KNN; ++k) {
    int j = il[k];
    float dx = __fsub_rn(lx[j], xi);
    float dy = __fsub_rn(ly[j], yi);
    float dz = __fsub_rn(lz[j], zi);
    ddx[k] = dx; ddy[k] = dy; ddz[k] = dz;
    double w = radius_i - dist[k];
    if (w < 0.0) w = 0.0;
    double dxd = dx, dyd = dy, dzd = dz;
    double wx = w * dxd, wy = w * dyd;
    c00 = fma(wx, dxd, c00);
    c01 = fma(wx, dyd, c01);
    c02 = fma(wx, dzd, c02);
    c11 = fma(wy, dyd, c11);
    c12 = fma(wy, dzd, c12);
    c22 = fma(w * dzd, dzd, c22);
    sw += w;
  }
  double inv = 1.0 / (sw + 1e-8);
  c00 *= inv; c01 *= inv; c02 *= inv; c11 *= inv; c12 *= inv; c22 *= inv;

  // cyclic Jacobi, 8 sweeps (overkill convergence for 3x3)
  double A00 = c00, A01 = c01, A02 = c02, A11 = c11, A12 = c12, A22 = c22;
  double v00 = 1, v01 = 0, v02 = 0,
         v10 = 0, v11 = 1, v12 = 0,
         v20 = 0, v21 = 0, v22 = 1;
  for (int sweep = 0; sweep < 8; ++sweep) {
    JROT(A00, A11, A01, A02, A12, v00, v01, v10, v11, v20, v21); // (p,q)=(0,1)
    JROT(A00, A22, A02, A01, A12, v00, v02, v10, v12, v20, v22); // (0,2)
    JROT(A11, A22, A12, A01, A02, v01, v02, v11, v12, v21, v22); // (1,2)
  }

  // smallest-eigenvalue eigenvector
  double nx, ny, nz;
  if (A00 <= A11 && A00 <= A22)      { nx = v00; ny = v10; nz = v20; }
  else if (A11 <= A22)               { nx = v01; ny = v11; nz = v21; }
  else                               { nx = v02; ny = v12; nz = v22; }
  double rn = 1.0 / sqrt(nx * nx + ny * ny + nz * nz);
  nx *= rn; ny *= rn; nz *= rn;

  // sign disambiguation: sum of signs of projections (self contributes 0)
  int s = 0;
#pragma unroll
  for (int k = 0; k < KNN; ++k) {
    double p = (double)ddx[k] * nx + (double)ddy[k] * ny + (double)ddz[k] * nz;
    s += (p > 0.0) - (p < 0.0);
  }
  if (s < 0) { nx = -nx; ny = -ny; nz = -nz; }

  const int gp = cloud * NPTS + i;
  normals[3 * gp + 0] = (float)nx;
  normals[3 * gp + 1] = (float)ny;
  normals[3 * gp + 2] = (float)nz;
#pragma unroll
  for (int k = 0; k < KNN; ++k) nbr_idx[gp * KNN + k] = il[k];

  // per-cloud radius = max over all f32 neighbor distances (positive-float bits
  // are order-isomorphic to uint)
  atomicMax(&radius_bits[cloud], __float_as_uint((float)radius_i));
}

// ---------------------------------------------------------------------------
// Kernel B1: per point, compute the 16 flat bins + normalization denominator.
// Bin formulas replicate the reference's f32 op sequence exactly.
// ---------------------------------------------------------------------------
__global__ __launch_bounds__(256) void bins_kernel(
    const float* __restrict__ verts,
    const float* __restrict__ normals,
    const int* __restrict__ nbr_idx,
    const unsigned int* __restrict__ radius_bits,
    unsigned short* __restrict__ bins, // (8*4096,16)
    float* __restrict__ denoms)        // (8*4096)
{
  const int gp = blockIdx.x * 256 + threadIdx.x; // 0..32767
  const int cloud = gp >> 12;
  const int i = gp & (NPTS - 1);
  const float* __restrict__ vb = verts + (size_t)cloud * NPTS * 3;
  const float xi = vb[3 * i + 0], yi = vb[3 * i + 1], zi = vb[3 * i + 2];
  const float nxi = normals[3 * gp + 0];
  const float nyi = normals[3 * gp + 1];
  const float nzi = normals[3 * gp + 2];
  const float radius = __uint_as_float(radius_bits[cloud]);
  const float rpe = __fadd_rn(radius, 1e-8f);
  const float PI_F = 3.14159274101257324f;    // f32(pi)
  const float TWOPI_F = 6.28318548202514648f; // f32(2*pi)

  int bl[KNN];
#pragma unroll
  for (int k = 0; k < KNN; ++k) {
    int j = nbr_idx[gp * KNN + k];
    float dx = __fsub_rn(vb[3 * j + 0], xi);
    float dy = __fsub_rn(vb[3 * j + 1], yi);
    float dz = __fsub_rn(vb[3 * j + 2], zi);
    double d2 = fma((double)dx, (double)dx,
                    fma((double)dy, (double)dy, (double)dz * (double)dz));
    float r = (float)sqrt(d2); // canonical f32 r; same path as kernel A radius

    // az bin: ((az + pi) / (2pi)) * 8, truncate, clip
    float az = (float)atan2((double)dy, (double)dx);
    int azb = (int)__fmul_rn(__fdiv_rn(__fadd_rn(az, PI_F), TWOPI_F), 8.0f);
    azb = min(max(azb, 0), 7);

    // el bin: ((z/(r+eps) + 1) * 0.5) * 2, truncate, clip
    float el = __fmul_rn(__fadd_rn(__fdiv_rn(dz, __fadd_rn(r, 1e-8f)), 1.0f), 0.5f);
    int elb = (int)__fmul_rn(el, 2.0f);
    elb = min(max(elb, 0), 1);

    // rad bin: (r/(radius+eps)) * 2, truncate, clip   (mask r<=radius is always 1)
    int rb = (int)__fmul_rn(__fdiv_rn(r, rpe), 2.0f);
    rb = min(max(rb, 0), 1);

    // h bin: ((cos+1)*0.5)*11, truncate, clip; cos = clipped dot of unit normals
    int gj = cloud * NPTS + j;
    double cd = (double)nxi * (double)normals[3 * gj + 0] +
                (double)nyi * (double)normals[3 * gj + 1] +
                (double)nzi * (double)normals[3 * gj + 2];
    cd = fmin(fmax(cd, -1.0), 1.0);
    float cf = (float)cd;
    int hb = (int)__fmul_rn(__fmul_rn(__fadd_rn(cf, 1.0f), 0.5f), 11.0f);
    hb = min(max(hb, 0), 10);

    bl[k] = ((azb * 2 + elb) * 2 + rb) * 11 + hb;
  }

  // ||descr||^2 = sum of squared counts = number of equal-bin ordered pairs (exact int)
  int pairs = 0;
#pragma unroll
  for (int a = 0; a < KNN; ++a)
#pragma unroll
    for (int b = 0; b < KNN; ++b) pairs += (bl[a] == bl[b]) ? 1 : 0;

  denoms[gp] = __fadd_rn(sqrtf((float)pairs), 1e-8f);
  unsigned short* bp = bins + (size_t)gp * KNN;
#pragma unroll
  for (int k = 0; k < KNN; ++k) bp[k] = (unsigned short)bl[k];
}

// ---------------------------------------------------------------------------
// Kernel B2: expand to dense (8,4096,352) output, coalesced writes.
// ---------------------------------------------------------------------------
__global__ __launch_bounds__(256) void out_kernel(
    const unsigned short* __restrict__ bins,
    const float* __restrict__ denoms,
    float* __restrict__ out)
{
  const int gid = blockIdx.x * 256 + threadIdx.x; // 0..11534335
  const int p = gid / TBINS;
  const int b = gid - p * TBINS;
  const unsigned short* __restrict__ bp = bins + (size_t)p * KNN;
  int c = 0;
#pragma unroll
  for (int k = 0; k < KNN; ++k) c += (bp[k] == (unsigned short)b) ? 1 : 0;
  out[gid] = __fdiv_rn((float)c, denoms[p]);
}

// ---------------------------------------------------------------------------
extern "C" void kernel_launch(void* const* d_in, const int* in_sizes, int n_in,
                              void* d_out, int out_size, void* d_ws, size_t ws_size,
                              hipStream_t stream) {
  const float* verts = (const float*)d_in[0]; // (8,4096,3) f32
  float* out = (float*)d_out;                 // (8,4096,352) f32

  // workspace layout (all offsets 16B-aligned)
  char* ws = (char*)d_ws;
  float* normals = (float*)ws;                              // 32768*3 f32 = 384 KiB
  int* nidx = (int*)(ws + 393216);                          // 32768*16 int = 2 MiB
  unsigned short* bins = (unsigned short*)(ws + 2490368);   // 32768*16 u16 = 1 MiB
  float* denoms = (float*)(ws + 3538944);                   // 32768 f32
  unsigned int* radb = (unsigned int*)(ws + 3670016);       // 8 u32
  // total needed: 3670048 bytes

  hipMemsetAsync(radb, 0, 8 * sizeof(unsigned int), stream);

  knn_normal_kernel<<<128, 256, 0, stream>>>(verts, normals, nidx, radb);
  bins_kernel<<<128, 256, 0, stream>>>(verts, normals, nidx, radb, bins, denoms);
  const int total = 8 * NPTS * TBINS; // 11534336, divisible by 256
  out_kernel<<<total / 256, 256, 0, stream>>>(bins, denoms, out);
}

// Round 7
// 738.145 us; speedup vs baseline: 2.4294x; 2.4294x over previous
//
#include <hip/hip_runtime.h>
#include <math.h>

#define NPTS 4096
#define KNN 16
#define TBINS 352
#define TCH 4                 // interleaved chunks per point (j == c mod 4)
#define PPB 64                // points per block
#define CLEN (NPTS / TCH)     // 1024 candidates per chunk

// ---------------------------------------------------------------------------
// Kernel A: brute-force 16-NN with reference-exact f32 d2, 4 lanes/point,
// in-wave shfl merge, then f64 cov + Jacobi eigensolver -> normal.
// ---------------------------------------------------------------------------

#define JROT(App, Aqq, Apq, Arp, Arq, V0p, V0q, V1p, V1q, V2p, V2q)            \
  do {                                                                         \
    double apq_ = Apq;                                                         \
    if (fabs(apq_) > 1e-300) {                                                 \
      double tau_ = (Aqq - App) / (2.0 * apq_);                                \
      double t_ = (tau_ >= 0.0) ? 1.0 / (tau_ + sqrt(1.0 + tau_ * tau_))       \
                                : 1.0 / (tau_ - sqrt(1.0 + tau_ * tau_));      \
      double c_ = 1.0 / sqrt(1.0 + t_ * t_);                                   \
      double s_ = t_ * c_;                                                     \
      App = App - t_ * apq_;                                                   \
      Aqq = Aqq + t_ * apq_;                                                   \
      Apq = 0.0;                                                               \
      double u_, w_;                                                           \
      u_ = Arp; w_ = Arq; Arp = c_ * u_ - s_ * w_; Arq = s_ * u_ + c_ * w_;    \
      u_ = V0p; w_ = V0q; V0p = c_ * u_ - s_ * w_; V0q = s_ * u_ + c_ * w_;    \
      u_ = V1p; w_ = V1q; V1p = c_ * u_ - s_ * w_; V1q = s_ * u_ + c_ * w_;    \
      u_ = V2p; w_ = V2q; V2p = c_ * u_ - s_ * w_; V2q = s_ * u_ + c_ * w_;    \
    }                                                                          \
  } while (0)

__global__ __launch_bounds__(256) void knn_normal_kernel(
    const float* __restrict__ verts,        // (8,4096,3)
    float* __restrict__ normals,            // (8*4096,3)
    int* __restrict__ nbr_idx,              // (8*4096,16)
    unsigned int* __restrict__ radius_bits) // (8), f32 bits, init 0
{
  __shared__ float lx[NPTS], ly[NPTS], lz[NPTS];
  const int blk = blockIdx.x;          // 512 blocks = 8 clouds * 64
  const int cloud = blk >> 6;
  const int pbase = (blk & 63) * PPB;
  const float* __restrict__ vb = verts + (size_t)cloud * NPTS * 3;
  for (int t = threadIdx.x; t < NPTS; t += 256) {
    lx[t] = vb[3 * t + 0];
    ly[t] = vb[3 * t + 1];
    lz[t] = vb[3 * t + 2];
  }
  __syncthreads();

  const int tid = (int)threadIdx.x;
  const int c = tid & 3;       // chunk id
  const int pl = tid >> 2;     // point within block, 0..63
  const int i = pbase + pl;    // local point index within cloud
  const float xi = lx[i], yi = ly[i], zi = lz[i];

  // ---- phase 1: per-lane sorted top-16 over chunk {j : j%4 == c} ----------
  // d2 replicates the reference f32 rounding exactly: (dx^2 + dy^2) + dz^2.
  // Within a chunk j is ascending, so strict < keeps lower index on ties
  // (matches jax.lax.top_k stability).
  float v[KNN];
  int id[KNN];
#pragma unroll
  for (int k = 0; k < KNN; ++k) { v[k] = INFINITY; id[k] = 0; }

  for (int s = 0; s < CLEN; ++s) {
    const int j = (s << 2) | c;
    float dx = __fsub_rn(lx[j], xi);
    float dy = __fsub_rn(ly[j], yi);
    float dz = __fsub_rn(lz[j], zi);
    float d2 = __fadd_rn(__fadd_rn(__fmul_rn(dx, dx), __fmul_rn(dy, dy)),
                         __fmul_rn(dz, dz));
    if (d2 < v[KNN - 1]) {
#pragma unroll
      for (int k = KNN - 1; k >= 1; --k) {
        bool ltm = d2 < v[k - 1];
        bool ltk = d2 < v[k];
        v[k]  = ltm ? v[k - 1]  : (ltk ? d2 : v[k]);
        id[k] = ltm ? id[k - 1] : (ltk ? j  : id[k]);
      }
      bool lt0 = d2 < v[0];
      id[0] = lt0 ? j : id[0];
      v[0]  = lt0 ? d2 : v[0];
    }
  }

  // ---- phase 2: in-wave merge of the 4 chunk lists (lex (d2, idx)) --------
  // Group = lanes lbase..lbase+3 (same point). Lane c==0 merges; source
  // lanes' lists stay untouched. Lex compare reproduces top_k tie-breaking
  // across chunks (indices interleave mod 4).
  const int lane = tid & 63;
  const int lbase = lane & ~3;
  for (int cc = 1; cc < 4; ++cc) {
#pragma unroll
    for (int k = 0; k < KNN; ++k) {
      float cv = __shfl(v[k], lbase + cc, 64);
      int ci = __shfl(id[k], lbase + cc, 64);
      bool lt15 = (cv < v[KNN - 1]) || (cv == v[KNN - 1] && ci < id[KNN - 1]);
      if (c == 0 && lt15) {
#pragma unroll
        for (int q = KNN - 1; q >= 1; --q) {
          bool ltm = (cv < v[q - 1]) || (cv == v[q - 1] && ci < id[q - 1]);
          bool ltk = (cv < v[q])     || (cv == v[q]     && ci < id[q]);
          v[q]  = ltm ? v[q - 1]  : (ltk ? cv : v[q]);
          id[q] = ltm ? id[q - 1] : (ltk ? ci : id[q]);
        }
        bool lt0 = (cv < v[0]) || (cv == v[0] && ci < id[0]);
        id[0] = lt0 ? ci : id[0];
        v[0]  = lt0 ? cv : v[0];
      }
    }
  }

  if (c != 0) return;

  // ---- phase 3: f64 covariance + Jacobi + sign vote (passing pipeline) ----
  double dist[KNN];
#pragma unroll
  for (int k = 0; k < KNN; ++k) dist[k] = sqrt((double)v[k]);
  const double radius_i = dist[KNN - 1];

  float ddx[KNN], ddy[KNN], ddz[KNN];
  double c00 = 0, c01 = 0, c02 = 0, c11 = 0, c12 = 0, c22 = 0, sw = 0;
#pragma unroll
  for (int k = 0; k < KNN; ++k) {
    int j = id[k];
    float dx = __fsub_rn(lx[j], xi);
    float dy = __fsub_rn(ly[j], yi);
    float dz = __fsub_rn(lz[j], zi);
    ddx[k] = dx; ddy[k] = dy; ddz[k] = dz;
    double w = radius_i - dist[k];
    if (w < 0.0) w = 0.0;
    double dxd = dx, dyd = dy, dzd = dz;
    double wx = w * dxd, wy = w * dyd;
    c00 = fma(wx, dxd, c00);
    c01 = fma(wx, dyd, c01);
    c02 = fma(wx, dzd, c02);
    c11 = fma(wy, dyd, c11);
    c12 = fma(wy, dzd, c12);
    c22 = fma(w * dzd, dzd, c22);
    sw += w;
  }
  double inv = 1.0 / (sw + 1e-8);
  c00 *= inv; c01 *= inv; c02 *= inv; c11 *= inv; c12 *= inv; c22 *= inv;

  double A00 = c00, A01 = c01, A02 = c02, A11 = c11, A12 = c12, A22 = c22;
  double v00 = 1, v01 = 0, v02 = 0,
         v10 = 0, v11 = 1, v12 = 0,
         v20 = 0, v21 = 0, v22 = 1;
  for (int sweep = 0; sweep < 8; ++sweep) {
    JROT(A00, A11, A01, A02, A12, v00, v01, v10, v11, v20, v21);
    JROT(A00, A22, A02, A01, A12, v00, v02, v10, v12, v20, v22);
    JROT(A11, A22, A12, A01, A02, v01, v02, v11, v12, v21, v22);
  }

  double nx, ny, nz;
  if (A00 <= A11 && A00 <= A22)      { nx = v00; ny = v10; nz = v20; }
  else if (A11 <= A22)               { nx = v01; ny = v11; nz = v21; }
  else                               { nx = v02; ny = v12; nz = v22; }
  double rn = 1.0 / sqrt(nx * nx + ny * ny + nz * nz);
  nx *= rn; ny *= rn; nz *= rn;

  int s = 0;
#pragma unroll
  for (int k = 0; k < KNN; ++k) {
    double p = (double)ddx[k] * nx + (double)ddy[k] * ny + (double)ddz[k] * nz;
    s += (p > 0.0) - (p < 0.0);
  }
  if (s < 0) { nx = -nx; ny = -ny; nz = -nz; }

  const int gp = cloud * NPTS + i;
  normals[3 * gp + 0] = (float)nx;
  normals[3 * gp + 1] = (float)ny;
  normals[3 * gp + 2] = (float)nz;
#pragma unroll
  for (int k = 0; k < KNN; ++k) nbr_idx[gp * KNN + k] = id[k];

  atomicMax(&radius_bits[cloud], __float_as_uint((float)radius_i));
}

// ---------------------------------------------------------------------------
// Kernel B1: per point, 16 flat bins + normalization denominator.
// r now comes from the reference-exact f32 d2 (bit-matches norm & radius).
// ---------------------------------------------------------------------------
__global__ __launch_bounds__(256) void bins_kernel(
    const float* __restrict__ verts,
    const float* __restrict__ normals,
    const int* __restrict__ nbr_idx,
    const unsigned int* __restrict__ radius_bits,
    unsigned short* __restrict__ bins, // (8*4096,16)
    float* __restrict__ denoms)        // (8*4096)
{
  const int gp = blockIdx.x * 256 + threadIdx.x; // 0..32767
  const int cloud = gp >> 12;
  const int i = gp & (NPTS - 1);
  const float* __restrict__ vb = verts + (size_t)cloud * NPTS * 3;
  const float xi = vb[3 * i + 0], yi = vb[3 * i + 1], zi = vb[3 * i + 2];
  const float nxi = normals[3 * gp + 0];
  const float nyi = normals[3 * gp + 1];
  const float nzi = normals[3 * gp + 2];
  const float radius = __uint_as_float(radius_bits[cloud]);
  const float rpe = __fadd_rn(radius, 1e-8f);
  const float PI_F = 3.14159274101257324f;
  const float TWOPI_F = 6.28318548202514648f;

  int bl[KNN];
#pragma unroll
  for (int k = 0; k < KNN; ++k) {
    int j = nbr_idx[gp * KNN + k];
    float dx = __fsub_rn(vb[3 * j + 0], xi);
    float dy = __fsub_rn(vb[3 * j + 1], yi);
    float dz = __fsub_rn(vb[3 * j + 2], zi);
    float d2f = __fadd_rn(__fadd_rn(__fmul_rn(dx, dx), __fmul_rn(dy, dy)),
                          __fmul_rn(dz, dz));
    float r = (float)sqrt((double)d2f); // correctly-rounded = reference norm

    float az = (float)atan2((double)dy, (double)dx);
    int azb = (int)__fmul_rn(__fdiv_rn(__fadd_rn(az, PI_F), TWOPI_F), 8.0f);
    azb = min(max(azb, 0), 7);

    float el = __fmul_rn(__fadd_rn(__fdiv_rn(dz, __fadd_rn(r, 1e-8f)), 1.0f), 0.5f);
    int elb = (int)__fmul_rn(el, 2.0f);
    elb = min(max(elb, 0), 1);

    int rb = (int)__fmul_rn(__fdiv_rn(r, rpe), 2.0f);
    rb = min(max(rb, 0), 1);

    int gj = cloud * NPTS + j;
    double cd = (double)nxi * (double)normals[3 * gj + 0] +
                (double)nyi * (double)normals[3 * gj + 1] +
                (double)nzi * (double)normals[3 * gj + 2];
    cd = fmin(fmax(cd, -1.0), 1.0);
    float cf = (float)cd;
    int hb = (int)__fmul_rn(__fmul_rn(__fadd_rn(cf, 1.0f), 0.5f), 11.0f);
    hb = min(max(hb, 0), 10);

    bl[k] = ((azb * 2 + elb) * 2 + rb) * 11 + hb;
  }

  int pairs = 0;
#pragma unroll
  for (int a = 0; a < KNN; ++a)
#pragma unroll
    for (int b = 0; b < KNN; ++b) pairs += (bl[a] == bl[b]) ? 1 : 0;

  denoms[gp] = __fadd_rn(sqrtf((float)pairs), 1e-8f);
  unsigned short* bp = bins + (size_t)gp * KNN;
#pragma unroll
  for (int k = 0; k < KNN; ++k) bp[k] = (unsigned short)bl[k];
}

// ---------------------------------------------------------------------------
// Kernel B2: expand to dense (8,4096,352) output, coalesced writes.
// ---------------------------------------------------------------------------
__global__ __launch_bounds__(256) void out_kernel(
    const unsigned short* __restrict__ bins,
    const float* __restrict__ denoms,
    float* __restrict__ out)
{
  const int gid = blockIdx.x * 256 + threadIdx.x;
  const int p = gid / TBINS;
  const int b = gid - p * TBINS;
  const unsigned short* __restrict__ bp = bins + (size_t)p * KNN;
  int c = 0;
#pragma unroll
  for (int k = 0; k < KNN; ++k) c += (bp[k] == (unsigned short)b) ? 1 : 0;
  out[gid] = __fdiv_rn((float)c, denoms[p]);
}

// ---------------------------------------------------------------------------
extern "C" void kernel_launch(void* const* d_in, const int* in_sizes, int n_in,
                              void* d_out, int out_size, void* d_ws, size_t ws_size,
                              hipStream_t stream) {
  const float* verts = (const float*)d_in[0]; // (8,4096,3) f32
  float* out = (float*)d_out;                 // (8,4096,352) f32

  char* ws = (char*)d_ws;
  float* normals = (float*)ws;                              // 384 KiB
  int* nidx = (int*)(ws + 393216);                          // 2 MiB
  unsigned short* bins = (unsigned short*)(ws + 2490368);   // 1 MiB
  float* denoms = (float*)(ws + 3538944);                   // 128 KiB
  unsigned int* radb = (unsigned int*)(ws + 3670016);       // 8 u32

  hipMemsetAsync(radb, 0, 8 * sizeof(unsigned int), stream);

  knn_normal_kernel<<<512, 256, 0, stream>>>(verts, normals, nidx, radb);
  bins_kernel<<<128, 256, 0, stream>>>(verts, normals, nidx, radb, bins, denoms);
  const int total = 8 * NPTS * TBINS; // 11534336
  out_kernel<<<total / 256, 256, 0, stream>>>(bins, denoms, out);
}

// Round 8
// 406.907 us; speedup vs baseline: 4.4070x; 1.8140x over previous
//
#include <hip/hip_runtime.h>
#include <math.h>

#define NPTS 4096
#define KNN 16
#define TBINS 352
#define PPB 16                 // points per block
#define LPP 16                 // lanes per point
#define CITER (NPTS / LPP)     // 256 candidates per lane
#define CAP 96                 // survivor capacity per point
#define BINOFF 210             // (bits>>22) offset: covers d2 in [2^-22, 2^9.5]

// ---------------------------------------------------------------------------
// sorted ascending insert into u64 K[16] (lex key = (d2bits<<32)|idx)
// ---------------------------------------------------------------------------
__device__ __forceinline__ void ins16(unsigned long long* K, unsigned long long key) {
  if (key < K[15]) {
#pragma unroll
    for (int q = 15; q >= 1; --q) {
      bool ltm = key < K[q - 1];
      bool ltk = key < K[q];
      K[q] = ltm ? K[q - 1] : (ltk ? key : K[q]);
    }
    if (key < K[0]) K[0] = key;
  }
}

#define JROT(App, Aqq, Apq, Arp, Arq, V0p, V0q, V1p, V1q, V2p, V2q)            \
  do {                                                                         \
    double apq_ = Apq;                                                         \
    if (fabs(apq_) > 1e-300) {                                                 \
      double tau_ = (Aqq - App) / (2.0 * apq_);                                \
      double t_ = (tau_ >= 0.0) ? 1.0 / (tau_ + sqrt(1.0 + tau_ * tau_))       \
                                : 1.0 / (tau_ - sqrt(1.0 + tau_ * tau_));      \
      double c_ = 1.0 / sqrt(1.0 + t_ * t_);                                   \
      double s_ = t_ * c_;                                                     \
      App = App - t_ * apq_;                                                   \
      Aqq = Aqq + t_ * apq_;                                                   \
      Apq = 0.0;                                                               \
      double u_, w_;                                                           \
      u_ = Arp; w_ = Arq; Arp = c_ * u_ - s_ * w_; Arq = s_ * u_ + c_ * w_;    \
      u_ = V0p; w_ = V0q; V0p = c_ * u_ - s_ * w_; V0q = s_ * u_ + c_ * w_;    \
      u_ = V1p; w_ = V1q; V1p = c_ * u_ - s_ * w_; V1q = s_ * u_ + c_ * w_;    \
      u_ = V2p; w_ = V2q; V2p = c_ * u_ - s_ * w_; V2q = s_ * u_ + c_ * w_;    \
    }                                                                          \
  } while (0)

__global__ __launch_bounds__(256, 2) void knn_hist_kernel(
    const float* __restrict__ verts,        // (8,4096,3)
    float* __restrict__ normals,            // (8*4096,3)
    int* __restrict__ nbr_idx,              // (8*4096,16)
    unsigned int* __restrict__ radius_bits) // (8)
{
  __shared__ float lxy[NPTS * 2];                 // 32 KiB (x,y interleaved)
  __shared__ float lz[NPTS];                      // 16 KiB
  __shared__ unsigned char hist[256][64];         // 16 KiB lane-private rows
  __shared__ unsigned short ptot[PPB][64];        //  2 KiB
  __shared__ unsigned long long surv[PPB][CAP];   // 12 KiB
  __shared__ unsigned int scnt[PPB];
  __shared__ unsigned int tbl[PPB];

  const int blk = blockIdx.x;       // 2048 blocks = 8 clouds * 256
  const int cloud = blk >> 8;
  const int pbase = (blk & 255) * PPB;
  const float* __restrict__ vb = verts + (size_t)cloud * NPTS * 3;
  const int tid = (int)threadIdx.x;

  for (int t = tid; t < NPTS; t += 256) {
    float a = vb[3 * t + 0], b = vb[3 * t + 1], cc = vb[3 * t + 2];
    lxy[2 * t] = a; lxy[2 * t + 1] = b; lz[t] = cc;
  }
  {
    unsigned int* h32 = (unsigned int*)hist;
#pragma unroll
    for (int k = 0; k < 16; ++k) h32[tid * 16 + k] = 0u;  // own row, pre-sync
  }
  if (tid < PPB) scnt[tid] = 0u;
  __syncthreads();

  const int p = tid >> 4;           // point-in-block
  const int c = tid & 15;           // lane-in-point
  const int i = pbase + p;
  const float xi = lxy[2 * i], yi = lxy[2 * i + 1], zi = lz[i];
  const int rot = ((tid >> 1) & 15) << 2;  // per-lane bin rotation (bank spread)

  // ---- pass 1: exact-bits histogram (divergence-free) ----------------------
#pragma unroll 4
  for (int s = 0; s < CITER; ++s) {
    int j = (s << 4) | c;
    float dx = __fsub_rn(lxy[2 * j], xi);
    float dy = __fsub_rn(lxy[2 * j + 1], yi);
    float dz = __fsub_rn(lz[j], zi);
    float d2 = __fadd_rn(__fadd_rn(__fmul_rn(dx, dx), __fmul_rn(dy, dy)),
                         __fmul_rn(dz, dz));
    int b = (int)(__float_as_uint(d2) >> 22) - BINOFF;
    b = min(max(b, 0), 63);
    hist[tid][(b + rot) & 63] += (unsigned char)1;
  }
  __syncthreads();

  // ---- reduce lane-private rows -> per-point totals ------------------------
#pragma unroll
  for (int bq = 0; bq < 4; ++bq) {
    int b = 4 * c + bq;
    unsigned int tot = 0;
    for (int r = 0; r < 16; ++r) {
      int row = p * 16 + r;
      int rrot = ((row >> 1) & 15) << 2;
      tot += hist[row][(b + rrot) & 63];
    }
    ptot[p][b] = (unsigned short)tot;
  }
  __syncthreads();

  // ---- exact threshold: first bin where cumcount >= 16 ---------------------
  if (c == 0) {
    unsigned int cum = 0; int B = 63;
    for (int b = 0; b < 64; ++b) {
      cum += ptot[p][b];
      if (cum >= KNN) { B = b; break; }
    }
    tbl[p] = (unsigned int)(B + 1 + BINOFF) << 22;  // d2bits < tbl <=> bin <= B
  }
  __syncthreads();

  // ---- pass 2: collect survivors (cheap rare-path append) ------------------
  {
    const unsigned int T = tbl[p];
#pragma unroll 4
    for (int s = 0; s < CITER; ++s) {
      int j = (s << 4) | c;
      float dx = __fsub_rn(lxy[2 * j], xi);
      float dy = __fsub_rn(lxy[2 * j + 1], yi);
      float dz = __fsub_rn(lz[j], zi);
      float d2 = __fadd_rn(__fadd_rn(__fmul_rn(dx, dx), __fmul_rn(dy, dy)),
                           __fmul_rn(dz, dz));
      unsigned int bits = __float_as_uint(d2);
      if (bits < T) {
        unsigned int pos = atomicAdd(&scnt[p], 1u);
        if (pos < CAP) surv[p][pos] = ((unsigned long long)bits << 32) | (unsigned int)j;
      }
    }
  }
  __syncthreads();

  if (c != 0) return;  // one handler lane per point from here on

  // ---- exact top-16 among survivors (lex (d2bits, idx) == top_k order) -----
  unsigned long long K[KNN];
#pragma unroll
  for (int k = 0; k < KNN; ++k) K[k] = 0xFFFFFFFFFFFFFFFFull;
  const int n = (int)scnt[p];
  if (n <= CAP) {
    for (int t = 0; t < n; ++t) ins16(K, surv[p][t]);
  } else {
    // never-expected exact fallback: serial full re-scan
    for (int j = 0; j < NPTS; ++j) {
      float dx = __fsub_rn(lxy[2 * j], xi);
      float dy = __fsub_rn(lxy[2 * j + 1], yi);
      float dz = __fsub_rn(lz[j], zi);
      float d2 = __fadd_rn(__fadd_rn(__fmul_rn(dx, dx), __fmul_rn(dy, dy)),
                           __fmul_rn(dz, dz));
      ins16(K, ((unsigned long long)__float_as_uint(d2) << 32) | (unsigned int)j);
    }
  }

  float v[KNN]; int id[KNN];
#pragma unroll
  for (int k = 0; k < KNN; ++k) {
    v[k] = __uint_as_float((unsigned int)(K[k] >> 32));
    id[k] = (int)(K[k] & 0xFFFFFFFFull);
  }

  // ---- phase 3: f64 covariance + Jacobi + sign vote (verified pipeline) ----
  double dist[KNN];
#pragma unroll
  for (int k = 0; k < KNN; ++k) dist[k] = sqrt((double)v[k]);
  const double radius_i = dist[KNN - 1];

  float ddx[KNN], ddy[KNN], ddz[KNN];
  double c00 = 0, c01 = 0, c02 = 0, c11 = 0, c12 = 0, c22 = 0, sw = 0;
#pragma unroll
  for (int k = 0; k < KNN; ++k) {
    int j = id[k];
    float dx = __fsub_rn(lxy[2 * j], xi);
    float dy = __fsub_rn(lxy[2 * j + 1], yi);
    float dz = __fsub_rn(lz[j], zi);
    ddx[k] = dx; ddy[k] = dy; ddz[k] = dz;
    double w = radius_i - dist[k];
    if (w < 0.0) w = 0.0;
    double dxd = dx, dyd = dy, dzd = dz;
    double wx = w * dxd, wy = w * dyd;
    c00 = fma(wx, dxd, c00);
    c01 = fma(wx, dyd, c01);
    c02 = fma(wx, dzd, c02);
    c11 = fma(wy, dyd, c11);
    c12 = fma(wy, dzd, c12);
    c22 = fma(w * dzd, dzd, c22);
    sw += w;
  }
  double inv = 1.0 / (sw + 1e-8);
  c00 *= inv; c01 *= inv; c02 *= inv; c11 *= inv; c12 *= inv; c22 *= inv;

  double A00 = c00, A01 = c01, A02 = c02, A11 = c11, A12 = c12, A22 = c22;
  double v00 = 1, v01 = 0, v02 = 0,
         v10 = 0, v11 = 1, v12 = 0,
         v20 = 0, v21 = 0, v22 = 1;
  for (int sweep = 0; sweep < 8; ++sweep) {
    JROT(A00, A11, A01, A02, A12, v00, v01, v10, v11, v20, v21);
    JROT(A00, A22, A02, A01, A12, v00, v02, v10, v12, v20, v22);
    JROT(A11, A22, A12, A01, A02, v01, v02, v11, v12, v21, v22);
  }

  double nx, ny, nz;
  if (A00 <= A11 && A00 <= A22)      { nx = v00; ny = v10; nz = v20; }
  else if (A11 <= A22)               { nx = v01; ny = v11; nz = v21; }
  else                               { nx = v02; ny = v12; nz = v22; }
  double rn = 1.0 / sqrt(nx * nx + ny * ny + nz * nz);
  nx *= rn; ny *= rn; nz *= rn;

  int sv = 0;
#pragma unroll
  for (int k = 0; k < KNN; ++k) {
    double pr = (double)ddx[k] * nx + (double)ddy[k] * ny + (double)ddz[k] * nz;
    sv += (pr > 0.0) - (pr < 0.0);
  }
  if (sv < 0) { nx = -nx; ny = -ny; nz = -nz; }

  const int gp = cloud * NPTS + i;
  normals[3 * gp + 0] = (float)nx;
  normals[3 * gp + 1] = (float)ny;
  normals[3 * gp + 2] = (float)nz;
#pragma unroll
  for (int k = 0; k < KNN; ++k) nbr_idx[gp * KNN + k] = id[k];

  atomicMax(&radius_bits[cloud], __float_as_uint((float)radius_i));
}

// ---------------------------------------------------------------------------
// Kernel B1: per point, 16 flat bins + normalization denominator (unchanged).
// ---------------------------------------------------------------------------
__global__ __launch_bounds__(256) void bins_kernel(
    const float* __restrict__ verts,
    const float* __restrict__ normals,
    const int* __restrict__ nbr_idx,
    const unsigned int* __restrict__ radius_bits,
    unsigned short* __restrict__ bins,
    float* __restrict__ denoms)
{
  const int gp = blockIdx.x * 256 + threadIdx.x;
  const int cloud = gp >> 12;
  const int i = gp & (NPTS - 1);
  const float* __restrict__ vb = verts + (size_t)cloud * NPTS * 3;
  const float xi = vb[3 * i + 0], yi = vb[3 * i + 1], zi = vb[3 * i + 2];
  const float nxi = normals[3 * gp + 0];
  const float nyi = normals[3 * gp + 1];
  const float nzi = normals[3 * gp + 2];
  const float radius = __uint_as_float(radius_bits[cloud]);
  const float rpe = __fadd_rn(radius, 1e-8f);
  const float PI_F = 3.14159274101257324f;
  const float TWOPI_F = 6.28318548202514648f;

  int bl[KNN];
#pragma unroll
  for (int k = 0; k < KNN; ++k) {
    int j = nbr_idx[gp * KNN + k];
    float dx = __fsub_rn(vb[3 * j + 0], xi);
    float dy = __fsub_rn(vb[3 * j + 1], yi);
    float dz = __fsub_rn(vb[3 * j + 2], zi);
    float d2f = __fadd_rn(__fadd_rn(__fmul_rn(dx, dx), __fmul_rn(dy, dy)),
                          __fmul_rn(dz, dz));
    float r = (float)sqrt((double)d2f);

    float az = (float)atan2((double)dy, (double)dx);
    int azb = (int)__fmul_rn(__fdiv_rn(__fadd_rn(az, PI_F), TWOPI_F), 8.0f);
    azb = min(max(azb, 0), 7);

    float el = __fmul_rn(__fadd_rn(__fdiv_rn(dz, __fadd_rn(r, 1e-8f)), 1.0f), 0.5f);
    int elb = (int)__fmul_rn(el, 2.0f);
    elb = min(max(elb, 0), 1);

    int rb = (int)__fmul_rn(__fdiv_rn(r, rpe), 2.0f);
    rb = min(max(rb, 0), 1);

    int gj = cloud * NPTS + j;
    double cd = (double)nxi * (double)normals[3 * gj + 0] +
                (double)nyi * (double)normals[3 * gj + 1] +
                (double)nzi * (double)normals[3 * gj + 2];
    cd = fmin(fmax(cd, -1.0), 1.0);
    float cf = (float)cd;
    int hb = (int)__fmul_rn(__fmul_rn(__fadd_rn(cf, 1.0f), 0.5f), 11.0f);
    hb = min(max(hb, 0), 10);

    bl[k] = ((azb * 2 + elb) * 2 + rb) * 11 + hb;
  }

  int pairs = 0;
#pragma unroll
  for (int a = 0; a < KNN; ++a)
#pragma unroll
    for (int b = 0; b < KNN; ++b) pairs += (bl[a] == bl[b]) ? 1 : 0;

  denoms[gp] = __fadd_rn(sqrtf((float)pairs), 1e-8f);
  unsigned short* bp = bins + (size_t)gp * KNN;
#pragma unroll
  for (int k = 0; k < KNN; ++k) bp[k] = (unsigned short)bl[k];
}

// ---------------------------------------------------------------------------
// Kernel B2: expand to dense (8,4096,352) output (unchanged).
// ---------------------------------------------------------------------------
__global__ __launch_bounds__(256) void out_kernel(
    const unsigned short* __restrict__ bins,
    const float* __restrict__ denoms,
    float* __restrict__ out)
{
  const int gid = blockIdx.x * 256 + threadIdx.x;
  const int p = gid / TBINS;
  const int b = gid - p * TBINS;
  const unsigned short* __restrict__ bp = bins + (size_t)p * KNN;
  int c = 0;
#pragma unroll
  for (int k = 0; k < KNN; ++k) c += (bp[k] == (unsigned short)b) ? 1 : 0;
  out[gid] = __fdiv_rn((float)c, denoms[p]);
}

// ---------------------------------------------------------------------------
extern "C" void kernel_launch(void* const* d_in, const int* in_sizes, int n_in,
                              void* d_out, int out_size, void* d_ws, size_t ws_size,
                              hipStream_t stream) {
  const float* verts = (const float*)d_in[0];
  float* out = (float*)d_out;

  char* ws = (char*)d_ws;
  float* normals = (float*)ws;                              // 384 KiB
  int* nidx = (int*)(ws + 393216);                          // 2 MiB
  unsigned short* bins = (unsigned short*)(ws + 2490368);   // 1 MiB
  float* denoms = (float*)(ws + 3538944);                   // 128 KiB
  unsigned int* radb = (unsigned int*)(ws + 3670016);       // 8 u32

  hipMemsetAsync(radb, 0, 8 * sizeof(unsigned int), stream);

  knn_hist_kernel<<<2048, 256, 0, stream>>>(verts, normals, nidx, radb);
  bins_kernel<<<128, 256, 0, stream>>>(verts, normals, nidx, radb, bins, denoms);
  const int total = 8 * NPTS * TBINS;
  out_kernel<<<total / 256, 256, 0, stream>>>(bins, denoms, out);
}

// Round 10
// 344.552 us; speedup vs baseline: 5.2045x; 1.1810x over previous
//
#include <hip/hip_runtime.h>
#include <math.h>

#define NPTS 4096
#define KNN 16
#define TBINS 352
#define PPB 16                 // points per block
#define CITER (NPTS / 16)      // 256 candidates per lane (16 lanes/point)
#define CAP 96                 // survivor capacity per point
#define BINOFF 210             // (bits>>22) offset: bins cover d2 in [2^-22, ~2^9.5]
#define HROW 68                // hist row stride in bytes (17 dwords, coprime 32)

// ---------------------------------------------------------------------------
// sorted ascending insert into u64 K[16] (lex key = (d2bits<<32)|idx)
// ---------------------------------------------------------------------------
__device__ __forceinline__ void ins16(unsigned long long* K, unsigned long long key) {
  if (key < K[15]) {
#pragma unroll
    for (int q = 15; q >= 1; --q) {
      bool ltm = key < K[q - 1];
      bool ltk = key < K[q];
      K[q] = ltm ? K[q - 1] : (ltk ? key : K[q]);
    }
    if (key < K[0]) K[0] = key;
  }
}

#define JROT(App, Aqq, Apq, Arp, Arq, V0p, V0q, V1p, V1q, V2p, V2q)            \
  do {                                                                         \
    double apq_ = Apq;                                                         \
    if (fabs(apq_) > 1e-300) {                                                 \
      double tau_ = (Aqq - App) / (2.0 * apq_);                                \
      double t_ = (tau_ >= 0.0) ? 1.0 / (tau_ + sqrt(1.0 + tau_ * tau_))       \
                                : 1.0 / (tau_ - sqrt(1.0 + tau_ * tau_));      \
      double c_ = 1.0 / sqrt(1.0 + t_ * t_);                                   \
      double s_ = t_ * c_;                                                     \
      App = App - t_ * apq_;                                                   \
      Aqq = Aqq + t_ * apq_;                                                   \
      Apq = 0.0;                                                               \
      double u_, w_;                                                           \
      u_ = Arp; w_ = Arq; Arp = c_ * u_ - s_ * w_; Arq = s_ * u_ + c_ * w_;    \
      u_ = V0p; w_ = V0q; V0p = c_ * u_ - s_ * w_; V0q = s_ * u_ + c_ * w_;    \
      u_ = V1p; w_ = V1q; V1p = c_ * u_ - s_ * w_; V1q = s_ * u_ + c_ * w_;    \
      u_ = V2p; w_ = V2q; V2p = c_ * u_ - s_ * w_; V2q = s_ * u_ + c_ * w_;    \
    }                                                                          \
  } while (0)

__global__ __launch_bounds__(256, 4) void knn_hist_kernel(
    const float* __restrict__ verts,        // (8,4096,3)
    float* __restrict__ normals,            // (8*4096,3)
    int* __restrict__ nbr_idx,              // (8*4096,16)
    unsigned int* __restrict__ radius_bits) // (8)
{
  __shared__ unsigned char hist[256 * HROW];      // 17408 B, lane-private rows
  __shared__ unsigned short ptot[PPB][64];        //  2048 B
  __shared__ unsigned long long surv[PPB][CAP];   // 12288 B
  __shared__ unsigned int scnt[PPB];
  __shared__ unsigned int tbl[PPB];

  const int blk = blockIdx.x;       // 2048 blocks = 8 clouds * 256
  const int cloud = blk >> 8;
  const int pbase = (blk & 255) * PPB;
  const float* __restrict__ vb = verts + (size_t)cloud * NPTS * 3;
  const int tid = (int)threadIdx.x;

  {
    unsigned int* h32 = (unsigned int*)hist;
#pragma unroll
    for (int k = 0; k < 17; ++k) h32[tid * 17 + k] = 0u;  // own padded row
  }
  if (tid < PPB) scnt[tid] = 0u;
  __syncthreads();

  const int p = tid >> 4;           // point-in-block
  const int c = tid & 15;           // lane-in-point
  const int i = pbase + p;
  const float xi = vb[3 * i + 0], yi = vb[3 * i + 1], zi = vb[3 * i + 2];

  // ---- pass 1: exact-bits histogram (candidates streamed from L1/L2) ------
#pragma unroll 4
  for (int s = 0; s < CITER; ++s) {
    const int j = (s << 4) | c;
    const float* vp = vb + 3 * j;
    float dx = __fsub_rn(vp[0], xi);
    float dy = __fsub_rn(vp[1], yi);
    float dz = __fsub_rn(vp[2], zi);
    float d2 = __fadd_rn(__fadd_rn(__fmul_rn(dx, dx), __fmul_rn(dy, dy)),
                         __fmul_rn(dz, dz));
    int b = (int)(__float_as_uint(d2) >> 22) - BINOFF;
    b = min(max(b, 0), 63);
    hist[tid * HROW + b] += (unsigned char)1;
  }
  __syncthreads();

  // ---- reduce lane-private rows -> per-point totals ------------------------
#pragma unroll
  for (int bq = 0; bq < 4; ++bq) {
    int b = 4 * c + bq;
    unsigned int tot = 0;
    for (int r = 0; r < 16; ++r) tot += hist[(p * 16 + r) * HROW + b];
    ptot[p][b] = (unsigned short)tot;
  }
  __syncthreads();

  // ---- exact threshold: first bin where cumcount >= 16 ---------------------
  if (c == 0) {
    unsigned int cum = 0; int B = 63;
    for (int b = 0; b < 64; ++b) {
      cum += ptot[p][b];
      if (cum >= KNN) { B = b; break; }
    }
    // bin edge bounds bin contents only for B<63 (bin 63 is clamped);
    // B==63 -> accept everything (falls to exact serial path; data-unreachable)
    tbl[p] = (B >= 63) ? 0xFFFFFFFFu : ((unsigned int)(B + 1 + BINOFF) << 22);
  }
  __syncthreads();

  // ---- pass 2: collect survivors (cheap rare-path append) ------------------
  {
    const unsigned int T = tbl[p];
#pragma unroll 4
    for (int s = 0; s < CITER; ++s) {
      const int j = (s << 4) | c;
      const float* vp = vb + 3 * j;
      float dx = __fsub_rn(vp[0], xi);
      float dy = __fsub_rn(vp[1], yi);
      float dz = __fsub_rn(vp[2], zi);
      float d2 = __fadd_rn(__fadd_rn(__fmul_rn(dx, dx), __fmul_rn(dy, dy)),
                           __fmul_rn(dz, dz));
      unsigned int bits = __float_as_uint(d2);
      if (bits < T) {
        unsigned int pos = atomicAdd(&scnt[p], 1u);
        if (pos < CAP) surv[p][pos] = ((unsigned long long)bits << 32) | (unsigned int)j;
      }
    }
  }
  __syncthreads();

  if (c != 0) return;  // one handler lane per point from here on

  // ---- exact top-16 among survivors (lex (d2bits, idx) == top_k order) -----
  unsigned long long K[KNN];
#pragma unroll
  for (int k = 0; k < KNN; ++k) K[k] = 0xFFFFFFFFFFFFFFFFull;
  const int n = (int)scnt[p];
  if (n <= CAP) {
    for (int t = 0; t < n; ++t) ins16(K, surv[p][t]);
  } else {
    // exact fallback: serial full re-scan (never expected)
    for (int j = 0; j < NPTS; ++j) {
      const float* vp = vb + 3 * j;
      float dx = __fsub_rn(vp[0], xi);
      float dy = __fsub_rn(vp[1], yi);
      float dz = __fsub_rn(vp[2], zi);
      float d2 = __fadd_rn(__fadd_rn(__fmul_rn(dx, dx), __fmul_rn(dy, dy)),
                           __fmul_rn(dz, dz));
      ins16(K, ((unsigned long long)__float_as_uint(d2) << 32) | (unsigned int)j);
    }
  }

  float v[KNN]; int id[KNN];
#pragma unroll
  for (int k = 0; k < KNN; ++k) {
    v[k] = __uint_as_float((unsigned int)(K[k] >> 32));
    id[k] = (int)(K[k] & 0xFFFFFFFFull);
  }

  // ---- phase 3: f64 covariance + Jacobi + sign vote (verified pipeline) ----
  double dist[KNN];
#pragma unroll
  for (int k = 0; k < KNN; ++k) dist[k] = sqrt((double)v[k]);
  const double radius_i = dist[KNN - 1];

  float ddx[KNN], ddy[KNN], ddz[KNN];
  double c00 = 0, c01 = 0, c02 = 0, c11 = 0, c12 = 0, c22 = 0, sw = 0;
#pragma unroll
  for (int k = 0; k < KNN; ++k) {
    const float* vp = vb + 3 * id[k];
    float dx = __fsub_rn(vp[0], xi);
    float dy = __fsub_rn(vp[1], yi);
    float dz = __fsub_rn(vp[2], zi);
    ddx[k] = dx; ddy[k] = dy; ddz[k] = dz;
    double w = radius_i - dist[k];
    if (w < 0.0) w = 0.0;
    double dxd = dx, dyd = dy, dzd = dz;
    double wx = w * dxd, wy = w * dyd;
    c00 = fma(wx, dxd, c00);
    c01 = fma(wx, dyd, c01);
    c02 = fma(wx, dzd, c02);
    c11 = fma(wy, dyd, c11);
    c12 = fma(wy, dzd, c12);
    c22 = fma(w * dzd, dzd, c22);
    sw += w;
  }
  double inv = 1.0 / (sw + 1e-8);
  c00 *= inv; c01 *= inv; c02 *= inv; c11 *= inv; c12 *= inv; c22 *= inv;

  double A00 = c00, A01 = c01, A02 = c02, A11 = c11, A12 = c12, A22 = c22;
  double v00 = 1, v01 = 0, v02 = 0,
         v10 = 0, v11 = 1, v12 = 0,
         v20 = 0, v21 = 0, v22 = 1;
  for (int sweep = 0; sweep < 8; ++sweep) {
    JROT(A00, A11, A01, A02, A12, v00, v01, v10, v11, v20, v21);
    JROT(A00, A22, A02, A01, A12, v00, v02, v10, v12, v20, v22);
    JROT(A11, A22, A12, A01, A02, v01, v02, v11, v12, v21, v22);
  }

  double nx, ny, nz;
  if (A00 <= A11 && A00 <= A22)      { nx = v00; ny = v10; nz = v20; }
  else if (A11 <= A22)               { nx = v01; ny = v11; nz = v21; }
  else                               { nx = v02; ny = v12; nz = v22; }
  double rn = 1.0 / sqrt(nx * nx + ny * ny + nz * nz);
  nx *= rn; ny *= rn; nz *= rn;

  int sv = 0;
#pragma unroll
  for (int k = 0; k < KNN; ++k) {
    double pr = (double)ddx[k] * nx + (double)ddy[k] * ny + (double)ddz[k] * nz;
    sv += (pr > 0.0) - (pr < 0.0);
  }
  if (sv < 0) { nx = -nx; ny = -ny; nz = -nz; }

  const int gp = cloud * NPTS + i;
  normals[3 * gp + 0] = (float)nx;
  normals[3 * gp + 1] = (float)ny;
  normals[3 * gp + 2] = (float)nz;
#pragma unroll
  for (int k = 0; k < KNN; ++k) nbr_idx[gp * KNN + k] = id[k];

  atomicMax(&radius_bits[cloud], __float_as_uint((float)radius_i));
}

// ---------------------------------------------------------------------------
// Kernel B1: per point, 16 flat bins + normalization denominator (unchanged).
// ---------------------------------------------------------------------------
__global__ __launch_bounds__(256) void bins_kernel(
    const float* __restrict__ verts,
    const float* __restrict__ normals,
    const int* __restrict__ nbr_idx,
    const unsigned int* __restrict__ radius_bits,
    unsigned short* __restrict__ bins,
    float* __restrict__ denoms)
{
  const int gp = blockIdx.x * 256 + threadIdx.x;
  const int cloud = gp >> 12;
  const int i = gp & (NPTS - 1);
  const float* __restrict__ vb = verts + (size_t)cloud * NPTS * 3;
  const float xi = vb[3 * i + 0], yi = vb[3 * i + 1], zi = vb[3 * i + 2];
  const float nxi = normals[3 * gp + 0];
  const float nyi = normals[3 * gp + 1];
  const float nzi = normals[3 * gp + 2];
  const float radius = __uint_as_float(radius_bits[cloud]);
  const float rpe = __fadd_rn(radius, 1e-8f);
  const float PI_F = 3.14159274101257324f;
  const float TWOPI_F = 6.28318548202514648f;

  int bl[KNN];
#pragma unroll
  for (int k = 0; k < KNN; ++k) {
    int j = nbr_idx[gp * KNN + k];
    float dx = __fsub_rn(vb[3 * j + 0], xi);
    float dy = __fsub_rn(vb[3 * j + 1], yi);
    float dz = __fsub_rn(vb[3 * j + 2], zi);
    float d2f = __fadd_rn(__fadd_rn(__fmul_rn(dx, dx), __fmul_rn(dy, dy)),
                          __fmul_rn(dz, dz));
    float r = (float)sqrt((double)d2f);

    float az = (float)atan2((double)dy, (double)dx);
    int azb = (int)__fmul_rn(__fdiv_rn(__fadd_rn(az, PI_F), TWOPI_F), 8.0f);
    azb = min(max(azb, 0), 7);

    float el = __fmul_rn(__fadd_rn(__fdiv_rn(dz, __fadd_rn(r, 1e-8f)), 1.0f), 0.5f);
    int elb = (int)__fmul_rn(el, 2.0f);
    elb = min(max(elb, 0), 1);

    int rb = (int)__fmul_rn(__fdiv_rn(r, rpe), 2.0f);
    rb = min(max(rb, 0), 1);

    int gj = cloud * NPTS + j;
    double cd = (double)nxi * (double)normals[3 * gj + 0] +
                (double)nyi * (double)normals[3 * gj + 1] +
                (double)nzi * (double)normals[3 * gj + 2];
    cd = fmin(fmax(cd, -1.0), 1.0);
    float cf = (float)cd;
    int hb = (int)__fmul_rn(__fmul_rn(__fadd_rn(cf, 1.0f), 0.5f), 11.0f);
    hb = min(max(hb, 0), 10);

    bl[k] = ((azb * 2 + elb) * 2 + rb) * 11 + hb;
  }

  int pairs = 0;
#pragma unroll
  for (int a = 0; a < KNN; ++a)
#pragma unroll
    for (int b = 0; b < KNN; ++b) pairs += (bl[a] == bl[b]) ? 1 : 0;

  denoms[gp] = __fadd_rn(sqrtf((float)pairs), 1e-8f);
  unsigned short* bp = bins + (size_t)gp * KNN;
#pragma unroll
  for (int k = 0; k < KNN; ++k) bp[k] = (unsigned short)bl[k];
}

// ---------------------------------------------------------------------------
// Kernel B2: expand to dense (8,4096,352) output (unchanged).
// ---------------------------------------------------------------------------
__global__ __launch_bounds__(256) void out_kernel(
    const unsigned short* __restrict__ bins,
    const float* __restrict__ denoms,
    float* __restrict__ out)
{
  const int gid = blockIdx.x * 256 + threadIdx.x;
  const int p = gid / TBINS;
  const int b = gid - p * TBINS;
  const unsigned short* __restrict__ bp = bins + (size_t)p * KNN;
  int c = 0;
#pragma unroll
  for (int k = 0; k < KNN; ++k) c += (bp[k] == (unsigned short)b) ? 1 : 0;
  out[gid] = __fdiv_rn((float)c, denoms[p]);
}

// ---------------------------------------------------------------------------
extern "C" void kernel_launch(void* const* d_in, const int* in_sizes, int n_in,
                              void* d_out, int out_size, void* d_ws, size_t ws_size,
                              hipStream_t stream) {
  const float* verts = (const float*)d_in[0];
  float* out = (float*)d_out;

  char* ws = (char*)d_ws;
  float* normals = (float*)ws;                              // 384 KiB
  int* nidx = (int*)(ws + 393216);                          // 2 MiB
  unsigned short* bins = (unsigned short*)(ws + 2490368);   // 1 MiB
  float* denoms = (float*)(ws + 3538944);                   // 128 KiB
  unsigned int* radb = (unsigned int*)(ws + 3670016);       // 8 u32

  hipMemsetAsync(radb, 0, 8 * sizeof(unsigned int), stream);

  knn_hist_kernel<<<2048, 256, 0, stream>>>(verts, normals, nidx, radb);
  bins_kernel<<<128, 256, 0, stream>>>(verts, normals, nidx, radb, bins, denoms);
  const int total = 8 * NPTS * TBINS;
  out_kernel<<<total / 256, 256, 0, stream>>>(bins, denoms, out);
}